// Round 1
// baseline (3320.481 us; speedup 1.0000x reference)
//
#include <hip/hip_runtime.h>
#include <math.h>

#define B_      16
#define C_      512
#define HW_     4096
#define P_      1024
#define EPSN    1e-4f
#define TEMP_   20.0f
#define THRESH_ 0.95f
#define NEGINF_ -1e9f

#define MTILE 32
#define KTILE 8

#define PRED_OFF   0
#define ASSIGN_OFF 65536
#define GRID_OFF   131072

// ---------------- pool sup_y -> proto_grid + valid ----------------
__global__ void pool_y_kernel(const float* __restrict__ sup_y,
                              float* __restrict__ out_grid,
                              float* __restrict__ validf) {
    int p = blockIdx.x * blockDim.x + threadIdx.x;
    if (p >= P_) return;
    int b = p >> 6, cell = p & 63, gy = cell >> 3, gx = cell & 7;
    const float* base = sup_y + b * HW_ + gy * 8 * 64 + gx * 8;
    float s = 0.f;
    #pragma unroll
    for (int r = 0; r < 8; ++r)
        #pragma unroll
        for (int c = 0; c < 8; ++c) s += base[r * 64 + c];
    float avg = s * (1.0f / 64.0f);
    out_grid[p] = (avg < THRESH_) ? 0.0f : avg;
    validf[p]   = (avg > THRESH_) ? 1.0f : 0.0f;
}

// ---------------- pool sup_x -> pooledT[c][p] ----------------
// one wave per (b,c): coalesced row reads, butterfly reduce within gx groups
__global__ __launch_bounds__(64) void pool_x_kernel(const float* __restrict__ sup_x,
                                                    float* __restrict__ pooledT) {
    int blk = blockIdx.x;            // b*C_ + c
    int b = blk >> 9, c = blk & 511;
    int lane = threadIdx.x;          // 0..63 = w
    const float* base = sup_x + (size_t)(b * C_ + c) * HW_;
    float acc[8];
    #pragma unroll
    for (int g = 0; g < 8; ++g) acc[g] = 0.f;
    #pragma unroll
    for (int h = 0; h < 64; ++h) {
        float v = base[h * 64 + lane];
        acc[h >> 3] += v;
    }
    #pragma unroll
    for (int g = 0; g < 8; ++g) {
        acc[g] += __shfl_xor(acc[g], 1);
        acc[g] += __shfl_xor(acc[g], 2);
        acc[g] += __shfl_xor(acc[g], 4);
    }
    if ((lane & 7) == 0) {
        int gx = lane >> 3;
        #pragma unroll
        for (int gy = 0; gy < 8; ++gy) {
            int p = b * 64 + gy * 8 + gx;
            pooledT[c * P_ + p] = acc[gy] * (1.0f / 64.0f);
        }
    }
}

// ---------------- per-proto 1/max(norm,eps), zeroed if invalid ----------------
__global__ void proto_rnorm_kernel(const float* __restrict__ pooledT,
                                   const float* __restrict__ validf,
                                   float* __restrict__ rnv) {
    int p = blockIdx.x * blockDim.x + threadIdx.x;
    if (p >= P_) return;
    double ss = 0.0;
    for (int c = 0; c < C_; ++c) {
        double v = (double)pooledT[c * P_ + p];
        ss += v * v;
    }
    float nrm = (float)sqrt(ss);
    float rn = 1.0f / fmaxf(nrm, EPSN);
    rnv[p] = (validf[p] > 0.5f) ? rn : 0.0f;
}

// ---------------- per-pixel 1/max(||q||,eps) ----------------
__global__ void qnorm_kernel(const float* __restrict__ qry,
                             float* __restrict__ rq) {
    int m = blockIdx.x * blockDim.x + threadIdx.x;   // 0..65535
    int b = m >> 12, hw = m & 4095;
    const float* base = qry + (size_t)b * C_ * HW_ + hw;
    double ss = 0.0;
    for (int c = 0; c < C_; ++c) {
        double v = (double)base[(size_t)c * HW_];
        ss += v * v;
    }
    float nrm = (float)sqrt(ss);
    rq[m] = 1.0f / fmaxf(nrm, EPSN);
}

// ---------------- fused GEMM + softmax + argmax ----------------
// grid: B_*HW_/MTILE blocks, 512 threads (8 waves).
// wave w handles pixels m_base + w*4 .. +3 ; lane owns 16 protos:
// n(t) = (t>>2)*256 + lane*4 + (t&3)
__global__ __launch_bounds__(512) void main_kernel(const float* __restrict__ qry,
                                                   const float* __restrict__ pooledT,
                                                   const float* __restrict__ rnv,
                                                   const float* __restrict__ rq,
                                                   float* __restrict__ out) {
    __shared__ float As[KTILE][MTILE];
    __shared__ float Bs[KTILE][P_];

    int blk = blockIdx.x;             // 0..2047
    int b = blk >> 7;
    int mb = blk & 127;
    int m_base = mb * MTILE;
    int tid = threadIdx.x;
    int w = tid >> 6, lane = tid & 63;

    float acc[4][16];
    #pragma unroll
    for (int i = 0; i < 4; ++i)
        #pragma unroll
        for (int j = 0; j < 16; ++j) acc[i][j] = 0.f;

    const float* qb = qry + (size_t)b * C_ * HW_ + m_base;

    for (int kt = 0; kt < C_ / KTILE; ++kt) {
        int k0 = kt * KTILE;
        if (tid < 64) {
            int r = tid >> 3, c4 = (tid & 7) * 4;
            float4 v = *(const float4*)(qb + (size_t)(k0 + r) * HW_ + c4);
            *(float4*)&As[r][c4] = v;
        }
        {
            const float* src = pooledT + (size_t)(k0 + w) * P_;
            #pragma unroll
            for (int j = 0; j < 4; ++j) {
                float4 v = *(const float4*)(src + j * 256 + lane * 4);
                *(float4*)&Bs[w][j * 256 + lane * 4] = v;
            }
        }
        __syncthreads();
        #pragma unroll
        for (int kk = 0; kk < KTILE; ++kk) {
            float4 a4 = *(const float4*)&As[kk][w * 4];
            float av[4] = {a4.x, a4.y, a4.z, a4.w};
            #pragma unroll
            for (int j = 0; j < 4; ++j) {
                float4 b4 = *(const float4*)&Bs[kk][j * 256 + lane * 4];
                float bv[4] = {b4.x, b4.y, b4.z, b4.w};
                #pragma unroll
                for (int i = 0; i < 4; ++i)
                    #pragma unroll
                    for (int cc = 0; cc < 4; ++cc)
                        acc[i][j * 4 + cc] += av[i] * bv[cc];
            }
        }
        __syncthreads();
    }

    // per-lane proto scale factors (0 => invalid proto)
    float rn16[16];
    #pragma unroll
    for (int j = 0; j < 4; ++j) {
        float4 v = *(const float4*)(rnv + j * 256 + lane * 4);
        rn16[j * 4 + 0] = v.x; rn16[j * 4 + 1] = v.y;
        rn16[j * 4 + 2] = v.z; rn16[j * 4 + 3] = v.w;
    }

    int gm_base = b * HW_ + m_base + w * 4;

    #pragma unroll 1
    for (int i = 0; i < 4; ++i) {
        int gm = gm_base + i;
        float rqm = rq[gm];
        float scale = rqm * TEMP_;

        // per-lane top-2 (first-index tiebreak)
        float v1 = -3e38f, v2 = -3e38f;
        int   n1 = P_,     n2 = P_;
        #pragma unroll
        for (int t = 0; t < 16; ++t) {
            int n = (t >> 2) * 256 + lane * 4 + (t & 3);
            float dist = acc[i][t] * rn16[t] * scale;
            float lg = (rn16[t] > 0.f) ? dist : NEGINF_;
            if (lg > v1 || (lg == v1 && n < n1)) {
                v2 = v1; n2 = n1; v1 = lg; n1 = n;
            } else if (lg > v2 || (lg == v2 && n < n2)) {
                v2 = lg; n2 = n;
            }
        }
        // wave-reduce top-2
        #pragma unroll
        for (int off = 1; off < 64; off <<= 1) {
            float ov1 = __shfl_xor(v1, off), ov2 = __shfl_xor(v2, off);
            int   on1 = __shfl_xor(n1, off), on2 = __shfl_xor(n2, off);
            if (ov1 > v1 || (ov1 == v1 && on1 < n1)) {
                if (v1 > ov2 || (v1 == ov2 && n1 < on2)) { v2 = v1; n2 = n1; }
                else                                     { v2 = ov2; n2 = on2; }
                v1 = ov1; n1 = on1;
            } else {
                if (ov1 > v2 || (ov1 == v2 && on1 < n2)) { v2 = ov1; n2 = on1; }
            }
        }

        // softmax-weighted sum over protos
        float sume = 0.f, sumpv = 0.f;
        #pragma unroll
        for (int t = 0; t < 16; ++t) {
            float dist = acc[i][t] * rn16[t] * scale;
            float lg = (rn16[t] > 0.f) ? dist : NEGINF_;
            float e = __expf(lg - v1);
            sume  += e;
            sumpv += e * dist;   // invalid: e==0, dist==0
        }
        #pragma unroll
        for (int off = 1; off < 64; off <<= 1) {
            sume  += __shfl_xor(sume,  off);
            sumpv += __shfl_xor(sumpv, off);
        }
        float pred = sumpv / sume;

        // near-tie refinement: fp64 recompute of both candidate dists
        int best = n1;
        if (n2 < P_ && (v1 - v2) < 1e-3f) {
            const float* qcol = qry + (size_t)b * C_ * HW_ + (m_base + w * 4 + i);
            double d1 = 0.0, d2 = 0.0, s1 = 0.0, s2 = 0.0;
            for (int cc = lane; cc < C_; cc += 64) {
                double qv = (double)qcol[(size_t)cc * HW_];
                double p1 = (double)pooledT[cc * P_ + n1];
                double p2 = (double)pooledT[cc * P_ + n2];
                d1 += qv * p1; d2 += qv * p2;
                s1 += p1 * p1; s2 += p2 * p2;
            }
            #pragma unroll
            for (int off = 1; off < 64; off <<= 1) {
                d1 += __shfl_xor(d1, off); d2 += __shfl_xor(d2, off);
                s1 += __shfl_xor(s1, off); s2 += __shfl_xor(s2, off);
            }
            double f1 = d1 / fmax(sqrt(s1), (double)EPSN);
            double f2 = d2 / fmax(sqrt(s2), (double)EPSN);
            if (f2 > f1 || (f2 == f1 && n2 < n1)) best = n2;
        }

        if (lane == 0) {
            out[PRED_OFF + gm]   = pred;
            out[ASSIGN_OFF + gm] = (float)best;
        }
    }
}

extern "C" void kernel_launch(void* const* d_in, const int* in_sizes, int n_in,
                              void* d_out, int out_size, void* d_ws, size_t ws_size,
                              hipStream_t stream) {
    const float* qry   = (const float*)d_in[0];
    const float* sup_x = (const float*)d_in[1];
    const float* sup_y = (const float*)d_in[2];
    float* out = (float*)d_out;
    float* ws  = (float*)d_ws;

    float* pooledT = ws;                  // [C_][P_]  512*1024
    float* rnv     = pooledT + C_ * P_;   // [P_]
    float* validf  = rnv + P_;            // [P_]
    float* rq      = validf + P_;         // [B_*HW_] 65536

    pool_y_kernel<<<4, 256, 0, stream>>>(sup_y, out + GRID_OFF, validf);
    pool_x_kernel<<<B_ * C_, 64, 0, stream>>>(sup_x, pooledT);
    proto_rnorm_kernel<<<4, 256, 0, stream>>>(pooledT, validf, rnv);
    qnorm_kernel<<<256, 256, 0, stream>>>(qry, rq);
    main_kernel<<<B_ * HW_ / MTILE, 512, 0, stream>>>(qry, pooledT, rnv, rq, out);
}

// Round 2
// 1131.333 us; speedup vs baseline: 2.9350x; 2.9350x over previous
//
#include <hip/hip_runtime.h>
#include <math.h>

#define B_      16
#define C_      512
#define HW_     4096
#define P_      1024
#define EPSN    1e-4f
#define TEMP_   20.0f
#define THRESH_ 0.95f
#define NEGINF_ -1e9f

#define MTILE 64            // pixels per block; 8 waves -> 8 pixels per wave
#define KTILE 8

#define PRED_OFF   0
#define ASSIGN_OFF 65536
#define GRID_OFF   131072

// ---------------- pool sup_y -> proto_grid + valid ----------------
__global__ void pool_y_kernel(const float* __restrict__ sup_y,
                              float* __restrict__ out_grid,
                              float* __restrict__ validf) {
    int p = blockIdx.x * blockDim.x + threadIdx.x;
    if (p >= P_) return;
    int b = p >> 6, cell = p & 63, gy = cell >> 3, gx = cell & 7;
    const float* base = sup_y + b * HW_ + gy * 8 * 64 + gx * 8;
    float s = 0.f;
    #pragma unroll
    for (int r = 0; r < 8; ++r)
        #pragma unroll
        for (int c = 0; c < 8; ++c) s += base[r * 64 + c];
    float avg = s * (1.0f / 64.0f);
    out_grid[p] = (avg < THRESH_) ? 0.0f : avg;
    validf[p]   = (avg > THRESH_) ? 1.0f : 0.0f;
}

// ---------------- pool sup_x -> pooledT[c][p] ----------------
__global__ __launch_bounds__(64) void pool_x_kernel(const float* __restrict__ sup_x,
                                                    float* __restrict__ pooledT) {
    int blk = blockIdx.x;            // b*C_ + c
    int b = blk >> 9, c = blk & 511;
    int lane = threadIdx.x;
    const float* base = sup_x + (size_t)(b * C_ + c) * HW_;
    float acc[8];
    #pragma unroll
    for (int g = 0; g < 8; ++g) acc[g] = 0.f;
    #pragma unroll
    for (int h = 0; h < 64; ++h) {
        float v = base[h * 64 + lane];
        acc[h >> 3] += v;
    }
    #pragma unroll
    for (int g = 0; g < 8; ++g) {
        acc[g] += __shfl_xor(acc[g], 1);
        acc[g] += __shfl_xor(acc[g], 2);
        acc[g] += __shfl_xor(acc[g], 4);
    }
    if ((lane & 7) == 0) {
        int gx = lane >> 3;
        #pragma unroll
        for (int gy = 0; gy < 8; ++gy) {
            int p = b * 64 + gy * 8 + gx;
            pooledT[c * P_ + p] = acc[gy] * (1.0f / 64.0f);
        }
    }
}

// ---------------- per-proto 1/max(norm,eps), zeroed if invalid ----------------
__global__ void proto_rnorm_kernel(const float* __restrict__ pooledT,
                                   const float* __restrict__ validf,
                                   float* __restrict__ rnv) {
    int p = blockIdx.x * blockDim.x + threadIdx.x;
    if (p >= P_) return;
    double ss = 0.0;
    for (int c = 0; c < C_; ++c) {
        double v = (double)pooledT[c * P_ + p];
        ss += v * v;
    }
    float nrm = (float)sqrt(ss);
    float rn = 1.0f / fmaxf(nrm, EPSN);
    rnv[p] = (validf[p] > 0.5f) ? rn : 0.0f;
}

// ---------------- per-pixel 1/max(||q||,eps) ----------------
__global__ void qnorm_kernel(const float* __restrict__ qry,
                             float* __restrict__ rq) {
    int m = blockIdx.x * blockDim.x + threadIdx.x;   // 0..65535
    int b = m >> 12, hw = m & 4095;
    const float* base = qry + (size_t)b * C_ * HW_ + hw;
    double ss = 0.0;
    for (int c = 0; c < C_; ++c) {
        double v = (double)base[(size_t)c * HW_];
        ss += v * v;
    }
    float nrm = (float)sqrt(ss);
    rq[m] = 1.0f / fmaxf(nrm, EPSN);
}

// ---------------- fused GEMM + softmax + argmax ----------------
// grid: B_*HW_/MTILE = 1024 blocks, 512 threads (8 waves).
// wave w handles pixels m_base + w*8 .. +7 ; lane owns 16 protos:
// n(t) = (t>>2)*256 + lane*4 + (t&3)
// acc[8][16] MUST stay in VGPRs: every loop touching it is fully unrolled.
__global__ __launch_bounds__(512, 1) void main_kernel(const float* __restrict__ qry,
                                                      const float* __restrict__ pooledT,
                                                      const float* __restrict__ rnv,
                                                      const float* __restrict__ rq,
                                                      float* __restrict__ out) {
    __shared__ float As[KTILE][MTILE];   // [k][pixel]
    __shared__ float Bs[KTILE][P_];      // [k][proto]

    int blk = blockIdx.x;                // 0..1023
    int b = blk >> 6;
    int mb = blk & 63;
    int m_base = mb * MTILE;
    int tid = threadIdx.x;
    int w = tid >> 6, lane = tid & 63;

    float acc[8][16];
    #pragma unroll
    for (int i = 0; i < 8; ++i)
        #pragma unroll
        for (int j = 0; j < 16; ++j) acc[i][j] = 0.f;

    const float* qb = qry + (size_t)b * C_ * HW_ + m_base;

    for (int kt = 0; kt < C_ / KTILE; ++kt) {
        int k0 = kt * KTILE;
        // stage B row w (1024 floats = 4 KB) via async global->LDS, 16B/lane
        {
            const float* src = pooledT + (size_t)(k0 + w) * P_ + lane * 4;
            #pragma unroll
            for (int j = 0; j < 4; ++j) {
                __builtin_amdgcn_global_load_lds(
                    (const __attribute__((address_space(1))) void*)(src + j * 256),
                    (__attribute__((address_space(3))) void*)&Bs[w][j * 256],
                    16, 0, 0);
            }
        }
        // stage A: 8 rows x 64 pixels; waves 0,1 each cover 4 rows (1 KB)
        if (w < 2) {
            int r = w * 4 + (lane >> 4);
            int c4 = (lane & 15) * 4;
            const float* src = qb + (size_t)(k0 + r) * HW_ + c4;
            __builtin_amdgcn_global_load_lds(
                (const __attribute__((address_space(1))) void*)src,
                (__attribute__((address_space(3))) void*)&As[w * 4][0],
                16, 0, 0);
        }
        __syncthreads();
        #pragma unroll
        for (int kk = 0; kk < KTILE; ++kk) {
            float4 a0 = *(const float4*)&As[kk][w * 8];
            float4 a1 = *(const float4*)&As[kk][w * 8 + 4];
            float av[8] = {a0.x, a0.y, a0.z, a0.w, a1.x, a1.y, a1.z, a1.w};
            #pragma unroll
            for (int j = 0; j < 4; ++j) {
                float4 b4 = *(const float4*)&Bs[kk][j * 256 + lane * 4];
                float bv[4] = {b4.x, b4.y, b4.z, b4.w};
                #pragma unroll
                for (int i = 0; i < 8; ++i)
                    #pragma unroll
                    for (int cc = 0; cc < 4; ++cc)
                        acc[i][j * 4 + cc] += av[i] * bv[cc];
            }
        }
        __syncthreads();
    }

    // per-lane proto scale factors (0 => invalid proto)
    float rn16[16];
    #pragma unroll
    for (int j = 0; j < 4; ++j) {
        float4 v = *(const float4*)(rnv + j * 256 + lane * 4);
        rn16[j * 4 + 0] = v.x; rn16[j * 4 + 1] = v.y;
        rn16[j * 4 + 2] = v.z; rn16[j * 4 + 3] = v.w;
    }

    int gm_base = b * HW_ + m_base + w * 8;

    #pragma unroll
    for (int i = 0; i < 8; ++i) {        // FULL unroll: acc indexing stays static
        int gm = gm_base + i;
        float rqm = rq[gm];
        float scale = rqm * TEMP_;

        // per-lane top-2 (first-index tiebreak)
        float v1 = -3e38f, v2 = -3e38f;
        int   n1 = P_,     n2 = P_;
        #pragma unroll
        for (int t = 0; t < 16; ++t) {
            int n = (t >> 2) * 256 + lane * 4 + (t & 3);
            float dist = acc[i][t] * rn16[t] * scale;
            float lg = (rn16[t] > 0.f) ? dist : NEGINF_;
            if (lg > v1 || (lg == v1 && n < n1)) {
                v2 = v1; n2 = n1; v1 = lg; n1 = n;
            } else if (lg > v2 || (lg == v2 && n < n2)) {
                v2 = lg; n2 = n;
            }
        }
        // wave-reduce top-2
        #pragma unroll
        for (int off = 1; off < 64; off <<= 1) {
            float ov1 = __shfl_xor(v1, off), ov2 = __shfl_xor(v2, off);
            int   on1 = __shfl_xor(n1, off), on2 = __shfl_xor(n2, off);
            if (ov1 > v1 || (ov1 == v1 && on1 < n1)) {
                if (v1 > ov2 || (v1 == ov2 && n1 < on2)) { v2 = v1; n2 = n1; }
                else                                     { v2 = ov2; n2 = on2; }
                v1 = ov1; n1 = on1;
            } else {
                if (ov1 > v2 || (ov1 == v2 && on1 < n2)) { v2 = ov1; n2 = on1; }
            }
        }

        // softmax-weighted sum over protos
        float sume = 0.f, sumpv = 0.f;
        #pragma unroll
        for (int t = 0; t < 16; ++t) {
            float dist = acc[i][t] * rn16[t] * scale;
            float lg = (rn16[t] > 0.f) ? dist : NEGINF_;
            float e = __expf(lg - v1);
            sume  += e;
            sumpv += e * dist;   // invalid: e==0, dist==0
        }
        #pragma unroll
        for (int off = 1; off < 64; off <<= 1) {
            sume  += __shfl_xor(sume,  off);
            sumpv += __shfl_xor(sumpv, off);
        }
        float pred = sumpv / sume;

        // near-tie refinement: fp64 recompute of both candidate dists
        int best = n1;
        if (n2 < P_ && (v1 - v2) < 1e-3f) {
            const float* qcol = qry + (size_t)b * C_ * HW_ + (m_base + w * 8 + i);
            double d1 = 0.0, d2 = 0.0, s1 = 0.0, s2 = 0.0;
            for (int cc = lane; cc < C_; cc += 64) {
                double qv = (double)qcol[(size_t)cc * HW_];
                double p1 = (double)pooledT[cc * P_ + n1];
                double p2 = (double)pooledT[cc * P_ + n2];
                d1 += qv * p1; d2 += qv * p2;
                s1 += p1 * p1; s2 += p2 * p2;
            }
            #pragma unroll
            for (int off = 1; off < 64; off <<= 1) {
                d1 += __shfl_xor(d1, off); d2 += __shfl_xor(d2, off);
                s1 += __shfl_xor(s1, off); s2 += __shfl_xor(s2, off);
            }
            double f1 = d1 / fmax(sqrt(s1), (double)EPSN);
            double f2 = d2 / fmax(sqrt(s2), (double)EPSN);
            if (f2 > f1 || (f2 == f1 && n2 < n1)) best = n2;
        }

        if (lane == 0) {
            out[PRED_OFF + gm]   = pred;
            out[ASSIGN_OFF + gm] = (float)best;
        }
    }
}

extern "C" void kernel_launch(void* const* d_in, const int* in_sizes, int n_in,
                              void* d_out, int out_size, void* d_ws, size_t ws_size,
                              hipStream_t stream) {
    const float* qry   = (const float*)d_in[0];
    const float* sup_x = (const float*)d_in[1];
    const float* sup_y = (const float*)d_in[2];
    float* out = (float*)d_out;
    float* ws  = (float*)d_ws;

    float* pooledT = ws;                  // [C_][P_]  512*1024
    float* rnv     = pooledT + C_ * P_;   // [P_]
    float* validf  = rnv + P_;            // [P_]
    float* rq      = validf + P_;         // [B_*HW_] 65536

    pool_y_kernel<<<4, 256, 0, stream>>>(sup_y, out + GRID_OFF, validf);
    pool_x_kernel<<<B_ * C_, 64, 0, stream>>>(sup_x, pooledT);
    proto_rnorm_kernel<<<4, 256, 0, stream>>>(pooledT, validf, rnv);
    qnorm_kernel<<<256, 256, 0, stream>>>(qry, rq);
    main_kernel<<<B_ * HW_ / MTILE, 512, 0, stream>>>(qry, pooledT, rnv, rq, out);
}

// Round 4
// 688.658 us; speedup vs baseline: 4.8217x; 1.6428x over previous
//
#include <hip/hip_runtime.h>
#include <math.h>

#define B_      16
#define C_      512
#define HW_     4096
#define P_      1024
#define EPSN    1e-4f
#define TEMP_   20.0f
#define THRESH_ 0.95f
#define NEGINF_ -1e9f
#define TIE_THR 1e-3f

#define PRED_OFF   0
#define ASSIGN_OFF 65536
#define GRID_OFF   131072

typedef short short8 __attribute__((ext_vector_type(8)));
typedef float f32x16 __attribute__((ext_vector_type(16)));

__device__ inline unsigned short f2bf(float f) {
    unsigned u = __float_as_uint(f);
    unsigned r = u + 0x7fffu + ((u >> 16) & 1u);
    return (unsigned short)(r >> 16);
}
__device__ inline float bf2f(unsigned short h) {
    return __uint_as_float((unsigned)h << 16);
}

// ---------------- pool sup_y -> proto_grid + valid ----------------
__global__ void pool_y_kernel(const float* __restrict__ sup_y,
                              float* __restrict__ out_grid,
                              float* __restrict__ validf) {
    int p = blockIdx.x * blockDim.x + threadIdx.x;
    if (p >= P_) return;
    int b = p >> 6, cell = p & 63, gy = cell >> 3, gx = cell & 7;
    const float* base = sup_y + b * HW_ + gy * 8 * 64 + gx * 8;
    float s = 0.f;
    #pragma unroll
    for (int r = 0; r < 8; ++r)
        #pragma unroll
        for (int c = 0; c < 8; ++c) s += base[r * 64 + c];
    float avg = s * (1.0f / 64.0f);
    out_grid[p] = (avg < THRESH_) ? 0.0f : avg;
    validf[p]   = (avg > THRESH_) ? 1.0f : 0.0f;
}

// ---------------- pool sup_x -> pooledT[c][p], 4 channels/block ----------------
__global__ __launch_bounds__(256) void pool_x_kernel(const float* __restrict__ sup_x,
                                                     float* __restrict__ pooledT) {
    int blk = blockIdx.x * 4 + (threadIdx.x >> 6);   // b*C_ + c
    int b = blk >> 9, c = blk & 511;
    int lane = threadIdx.x & 63;
    const float* base = sup_x + (size_t)(b * C_ + c) * HW_;
    float acc[8];
    #pragma unroll
    for (int g = 0; g < 8; ++g) acc[g] = 0.f;
    #pragma unroll
    for (int h = 0; h < 64; ++h) {
        float v = base[h * 64 + lane];
        acc[h >> 3] += v;
    }
    #pragma unroll
    for (int g = 0; g < 8; ++g) {
        acc[g] += __shfl_xor(acc[g], 1);
        acc[g] += __shfl_xor(acc[g], 2);
        acc[g] += __shfl_xor(acc[g], 4);
    }
    if ((lane & 7) == 0) {
        int gx = lane >> 3;
        #pragma unroll
        for (int gy = 0; gy < 8; ++gy) {
            int p = b * 64 + gy * 8 + gx;
            pooledT[c * P_ + p] = acc[gy] * (1.0f / 64.0f);
        }
    }
}

// ---------------- per-proto 1/max(norm,eps), zeroed if invalid ----------------
__global__ void proto_rnorm_kernel(const float* __restrict__ pooledT,
                                   const float* __restrict__ validf,
                                   float* __restrict__ rnv) {
    int p = blockIdx.x * blockDim.x + threadIdx.x;
    if (p >= P_) return;
    double ss = 0.0;
    for (int c = 0; c < C_; ++c) {
        double v = (double)pooledT[c * P_ + p];
        ss += v * v;
    }
    float nrm = (float)sqrt(ss);
    float rn = 1.0f / fmaxf(nrm, EPSN);
    rnv[p] = (validf[p] > 0.5f) ? rn : 0.0f;
}

// ---------------- pack protos to MFMA B-fragment order, split hi/lo bf16 ----
// Bph/Bpl[sk][n][kh][j] : element c = sk*16 + kh*8 + j, n = proto. 1 MB each.
__global__ void pack_b_kernel(const float* __restrict__ pooledT,
                              short* __restrict__ Bph,
                              short* __restrict__ Bpl) {
    int n = blockIdx.x * 256 + threadIdx.x;   // 0..1023
    for (int c8 = 0; c8 < 64; ++c8) {
        unsigned short vh[8], vl[8];
        #pragma unroll
        for (int j = 0; j < 8; ++j) {
            float p = pooledT[(c8 * 8 + j) * P_ + n];
            unsigned short h = f2bf(p);
            vh[j] = h;
            vl[j] = f2bf(p - bf2f(h));
        }
        uint4 uh, ul;
        uh.x = (unsigned)vh[0] | ((unsigned)vh[1] << 16);
        uh.y = (unsigned)vh[2] | ((unsigned)vh[3] << 16);
        uh.z = (unsigned)vh[4] | ((unsigned)vh[5] << 16);
        uh.w = (unsigned)vh[6] | ((unsigned)vh[7] << 16);
        ul.x = (unsigned)vl[0] | ((unsigned)vl[1] << 16);
        ul.y = (unsigned)vl[2] | ((unsigned)vl[3] << 16);
        ul.z = (unsigned)vl[4] | ((unsigned)vl[5] << 16);
        ul.w = (unsigned)vl[6] | ((unsigned)vl[7] << 16);
        int sk = c8 >> 1, kh = c8 & 1;
        *(uint4*)&Bph[sk * 16384 + n * 16 + kh * 8] = uh;
        *(uint4*)&Bpl[sk * 16384 + n * 16 + kh * 8] = ul;
    }
}

// ---------------- fused MFMA GEMM + softmax + argmax ----------------
// grid 1024 blocks (64 pixels each), 512 threads (8 waves).
// wave w: N-range [w*128, w*128+128); 2 m-tiles x 4 n-tiles of 32x32.
// 3-pass split: dist = ah*bh + al*bh + ah*bl  (al*bl dropped; noise ~1e-5)
// B fragments: register-prefetched straight from L2 (no LDS for B).
__global__ __launch_bounds__(512, 2) void gemm_fused_kernel(
        const float* __restrict__ qry,
        const short* __restrict__ Bph,
        const short* __restrict__ Bpl,
        const float* __restrict__ pooledT,
        const float* __restrict__ rnv,
        float* __restrict__ out) {
    __shared__ short Ah[2][64 * 16];      // [buf][pixel*16 + klocal]
    __shared__ short Al[2][64 * 16];
    __shared__ float ss_tab[8][64];
    __shared__ float rq_s[64];
    __shared__ float st[64][8][6];        // per-row per-wave {v1,v2,n1,n2,se,sv}
    __shared__ int rowinfo[64];

    int m0 = blockIdx.x * 64;
    int b = m0 >> 12;
    int hw0 = m0 & 4095;
    int tid = threadIdx.x;
    int w = tid >> 6;
    int lane = tid & 63;
    int hl = lane & 31, half = lane >> 5;
    int nb = w * 128;

    const float* qb = qry + (size_t)b * (C_ * HW_) + hw0;
    // per-lane fragment byte base: n = nb + hl (+nt*32), k-half = half*8
    const short* bh_base = Bph + ((nb + hl) * 16 + half * 8);
    const short* bl_base = Bpl + ((nb + hl) * 16 + half * 8);

    f32x16 zero16 = {0.f,0.f,0.f,0.f,0.f,0.f,0.f,0.f,0.f,0.f,0.f,0.f,0.f,0.f,0.f,0.f};
    f32x16 acc[2][4];
    #pragma unroll
    for (int mt = 0; mt < 2; ++mt)
        #pragma unroll
        for (int nt = 0; nt < 4; ++nt) acc[mt][nt] = zero16;

    float ss = 0.f;

    // ---- prologue: stage A sk=0, load B frags sk=0 ----
    short8 bhc[4], blc[4];
    {
        float q0 = qb[(size_t)(w * 2) * HW_ + lane];
        float q1 = qb[(size_t)(w * 2 + 1) * HW_ + lane];
        unsigned short h0 = f2bf(q0), h1 = f2bf(q1);
        float r0 = q0 - bf2f(h0), r1 = q1 - bf2f(h1);
        unsigned short l0 = f2bf(r0), l1 = f2bf(r1);
        *(unsigned*)&Ah[0][lane * 16 + w * 2] = (unsigned)h0 | ((unsigned)h1 << 16);
        *(unsigned*)&Al[0][lane * 16 + w * 2] = (unsigned)l0 | ((unsigned)l1 << 16);
        ss += q0 * q0 + q1 * q1;
        #pragma unroll
        for (int nt = 0; nt < 4; ++nt) {
            bhc[nt] = *(const short8*)(bh_base + nt * 512);
            blc[nt] = *(const short8*)(bl_base + nt * 512);
        }
    }
    __syncthreads();

    // ---- K loop ----
    for (int sk = 0; sk < 32; ++sk) {
        int buf = sk & 1, nbuf = buf ^ 1, nsk = sk + 1;
        short8 bhn[4], bln[4];
        float q0 = 0.f, q1 = 0.f;
        if (nsk < 32) {
            const short* bh_p = bh_base + nsk * 16384;
            const short* bl_p = bl_base + nsk * 16384;
            #pragma unroll
            for (int nt = 0; nt < 4; ++nt) {
                bhn[nt] = *(const short8*)(bh_p + nt * 512);
                bln[nt] = *(const short8*)(bl_p + nt * 512);
            }
            q0 = qb[(size_t)(nsk * 16 + w * 2) * HW_ + lane];
            q1 = qb[(size_t)(nsk * 16 + w * 2 + 1) * HW_ + lane];
        }
        short8 ahf[2], alf[2];
        #pragma unroll
        for (int mt = 0; mt < 2; ++mt) {
            ahf[mt] = *(const short8*)&Ah[buf][(mt * 32 + hl) * 16 + half * 8];
            alf[mt] = *(const short8*)&Al[buf][(mt * 32 + hl) * 16 + half * 8];
        }
        #pragma unroll
        for (int nt = 0; nt < 4; ++nt) {
            #pragma unroll
            for (int mt = 0; mt < 2; ++mt) {
                acc[mt][nt] = __builtin_amdgcn_mfma_f32_32x32x16_bf16(ahf[mt], bhc[nt], acc[mt][nt], 0, 0, 0);
                acc[mt][nt] = __builtin_amdgcn_mfma_f32_32x32x16_bf16(alf[mt], bhc[nt], acc[mt][nt], 0, 0, 0);
                acc[mt][nt] = __builtin_amdgcn_mfma_f32_32x32x16_bf16(ahf[mt], blc[nt], acc[mt][nt], 0, 0, 0);
            }
        }
        if (nsk < 32) {
            unsigned short h0 = f2bf(q0), h1 = f2bf(q1);
            float r0 = q0 - bf2f(h0), r1 = q1 - bf2f(h1);
            unsigned short l0 = f2bf(r0), l1 = f2bf(r1);
            *(unsigned*)&Ah[nbuf][lane * 16 + w * 2] = (unsigned)h0 | ((unsigned)h1 << 16);
            *(unsigned*)&Al[nbuf][lane * 16 + w * 2] = (unsigned)l0 | ((unsigned)l1 << 16);
            ss += q0 * q0 + q1 * q1;
            #pragma unroll
            for (int nt = 0; nt < 4; ++nt) { bhc[nt] = bhn[nt]; blc[nt] = bln[nt]; }
        }
        __syncthreads();
    }

    // ---- query norms ----
    ss_tab[w][lane] = ss;
    __syncthreads();
    if (tid < 64) {
        float s = 0.f;
        #pragma unroll
        for (int q = 0; q < 8; ++q) s += ss_tab[q][tid];
        rq_s[tid] = 1.0f / fmaxf(sqrtf(s), EPSN);
    }
    __syncthreads();

    // ---- per-wave epilogue: scale, top2, softmax sums over this wave's 128 n ----
    float rn4[4];
    #pragma unroll
    for (int nt = 0; nt < 4; ++nt) rn4[nt] = rnv[nb + nt * 32 + hl];

    #pragma unroll
    for (int mt = 0; mt < 2; ++mt) {
        #pragma unroll
        for (int r = 0; r < 16; ++r) {
            int mrow = mt * 32 + (r & 3) + 8 * (r >> 2) + 4 * half;
            float scale = rq_s[mrow] * TEMP_;
            float d4[4], lg4[4];
            float v1 = -3e38f, v2 = -3e38f;
            int n1 = P_, n2 = P_;
            #pragma unroll
            for (int nt = 0; nt < 4; ++nt) {
                float dd = acc[mt][nt][r] * rn4[nt] * scale;
                float lg = (rn4[nt] > 0.f) ? dd : NEGINF_;
                d4[nt] = dd; lg4[nt] = lg;
                int n = nb + nt * 32 + hl;
                if (lg > v1 || (lg == v1 && n < n1)) {
                    v2 = v1; n2 = n1; v1 = lg; n1 = n;
                } else if (lg > v2 || (lg == v2 && n < n2)) {
                    v2 = lg; n2 = n;
                }
            }
            #pragma unroll
            for (int off = 1; off < 32; off <<= 1) {
                float ov1 = __shfl_xor(v1, off), ov2 = __shfl_xor(v2, off);
                int   on1 = __shfl_xor(n1, off), on2 = __shfl_xor(n2, off);
                if (ov1 > v1 || (ov1 == v1 && on1 < n1)) {
                    if (v1 > ov2 || (v1 == ov2 && n1 < on2)) { v2 = v1; n2 = n1; }
                    else                                     { v2 = ov2; n2 = on2; }
                    v1 = ov1; n1 = on1;
                } else {
                    if (ov1 > v2 || (ov1 == v2 && on1 < n2)) { v2 = ov1; n2 = on1; }
                }
            }
            float se = 0.f, sv = 0.f;
            #pragma unroll
            for (int nt = 0; nt < 4; ++nt) {
                float e = __expf(lg4[nt] - v1);
                se += e;
                sv += e * d4[nt];
            }
            #pragma unroll
            for (int off = 1; off < 32; off <<= 1) {
                se += __shfl_xor(se, off);
                sv += __shfl_xor(sv, off);
            }
            if (hl == 0) {
                float* s6 = st[mrow][w];
                s6[0] = v1; s6[1] = v2;
                s6[2] = __int_as_float(n1); s6[3] = __int_as_float(n2);
                s6[4] = se; s6[5] = sv;
            }
        }
    }
    __syncthreads();

    // ---- cross-wave merge: wave w handles rows w*8..w*8+7, 8 lanes per row ----
    {
        int row = w * 8 + (lane >> 3), s = lane & 7;
        float v1 = st[row][s][0], v2 = st[row][s][1];
        int n1 = __float_as_int(st[row][s][2]), n2 = __float_as_int(st[row][s][3]);
        float se = st[row][s][4], sv = st[row][s][5];
        #pragma unroll
        for (int off = 1; off < 8; off <<= 1) {
            float ov1 = __shfl_xor(v1, off), ov2 = __shfl_xor(v2, off);
            int   on1 = __shfl_xor(n1, off), on2 = __shfl_xor(n2, off);
            float ose = __shfl_xor(se, off), osv = __shfl_xor(sv, off);
            float myv1 = v1;
            float mv1, mv2; int mn1, mn2;
            if (ov1 > v1 || (ov1 == v1 && on1 < n1)) {
                mv1 = ov1; mn1 = on1;
                if (v1 > ov2 || (v1 == ov2 && n1 < on2)) { mv2 = v1; mn2 = n1; }
                else                                     { mv2 = ov2; mn2 = on2; }
            } else {
                mv1 = v1; mn1 = n1;
                if (ov1 > v2 || (ov1 == v2 && on1 < n2)) { mv2 = ov1; mn2 = on1; }
                else                                     { mv2 = v2; mn2 = n2; }
            }
            float fa = __expf(myv1 - mv1), fb = __expf(ov1 - mv1);
            se = se * fa + ose * fb;
            sv = sv * fa + osv * fb;
            v1 = mv1; n1 = mn1; v2 = mv2; n2 = mn2;
        }
        if (s == 0) {
            int gm = m0 + row;
            out[PRED_OFF + gm] = sv / se;
            bool flagged = (n2 < P_) && ((v1 - v2) < TIE_THR);
            if (!flagged) out[ASSIGN_OFF + gm] = (float)n1;
            rowinfo[row] = flagged ? (n1 | (n2 << 16)) : -1;
        }
    }
    __syncthreads();

    // ---- fp64 tie refinement (wave 0, cooperative) ----
    if (w == 0) {
        for (int row = 0; row < 64; ++row) {
            int info = rowinfo[row];
            if (info < 0) continue;
            int n1 = info & 0xffff, n2 = info >> 16;
            const float* qcol = qb + row;
            double d1 = 0.0, d2 = 0.0, s1 = 0.0, s2 = 0.0;
            for (int cc = lane; cc < C_; cc += 64) {
                double qv = (double)qcol[(size_t)cc * HW_];
                double p1 = (double)pooledT[cc * P_ + n1];
                double p2 = (double)pooledT[cc * P_ + n2];
                d1 += qv * p1; d2 += qv * p2;
                s1 += p1 * p1; s2 += p2 * p2;
            }
            #pragma unroll
            for (int off = 1; off < 64; off <<= 1) {
                d1 += __shfl_xor(d1, off); d2 += __shfl_xor(d2, off);
                s1 += __shfl_xor(s1, off); s2 += __shfl_xor(s2, off);
            }
            double f1 = d1 / fmax(sqrt(s1), (double)EPSN);
            double f2 = d2 / fmax(sqrt(s2), (double)EPSN);
            int best = (f2 > f1 || (f2 == f1 && n2 < n1)) ? n2 : n1;
            if (lane == 0) out[ASSIGN_OFF + m0 + row] = (float)best;
        }
    }
}

extern "C" void kernel_launch(void* const* d_in, const int* in_sizes, int n_in,
                              void* d_out, int out_size, void* d_ws, size_t ws_size,
                              hipStream_t stream) {
    const float* qry   = (const float*)d_in[0];
    const float* sup_x = (const float*)d_in[1];
    const float* sup_y = (const float*)d_in[2];
    float* out = (float*)d_out;
    float* ws  = (float*)d_ws;

    float* pooledT = ws;                       // 512*1024 f32 = 2 MB
    float* rnv     = pooledT + C_ * P_;        // 1024
    float* validf  = rnv + P_;                 // 1024
    short* Bph     = (short*)(validf + P_);    // 32*1024*16 bf16 = 1 MB
    short* Bpl     = Bph + 32 * 1024 * 16;     // 1 MB

    pool_y_kernel<<<4, 256, 0, stream>>>(sup_y, out + GRID_OFF, validf);
    pool_x_kernel<<<B_ * C_ / 4, 256, 0, stream>>>(sup_x, pooledT);
    proto_rnorm_kernel<<<4, 256, 0, stream>>>(pooledT, validf, rnv);
    pack_b_kernel<<<4, 256, 0, stream>>>(pooledT, Bph, Bpl);
    gemm_fused_kernel<<<B_ * HW_ / 64, 512, 0, stream>>>(qry, Bph, Bpl, pooledT, rnv, out);
}